// Round 15
// baseline (195.458 us; speedup 1.0000x reference)
//
#include <hip/hip_runtime.h>

#define K_DIM 4096
#define N_DIM 4096
#define NT (K_DIM / 64)  // 64 K-tiles, 64 bytes deep each

typedef int v4i __attribute__((ext_vector_type(4)));

__device__ __forceinline__ void gload_lds16(const void* g, void* l) {
  __builtin_amdgcn_global_load_lds(
      (const __attribute__((address_space(1))) void*)g,
      (__attribute__((address_space(3))) void*)l, 16, 0, 0);
}

__device__ __forceinline__ int pack4(int4 w) {
  return (w.x & 0xff) | ((w.y & 0xff) << 8) | ((w.z & 0xff) << 16) | (w.w << 24);
}

// fused int32 -> int8 pack for x and w (d_ws layout is contiguous: x then w)
__global__ __launch_bounds__(256) void pack_kernel(const int* __restrict__ x,
                                                   const int* __restrict__ w,
                                                   int4* __restrict__ dst, int n16x,
                                                   int n16) {
  int i = blockIdx.x * 256 + threadIdx.x;
  if (i >= n16) return;
  const int4* s = (i < n16x) ? ((const int4*)x + (size_t)i * 4)
                             : ((const int4*)w + (size_t)(i - n16x) * 4);
  int4 w0 = s[0], w1 = s[1], w2 = s[2], w3 = s[3];
  int4 r;
  r.x = pack4(w0); r.y = pack4(w1); r.z = pack4(w2); r.w = pack4(w3);
  dst[i] = r;
}

// 256x256 tile, BK=64 bytes, 8 waves (2M x 4N), mfma_i32_16x16x64_i8.
// REGISTER-LEVEL FRAGMENT DOUBLE-BUFFER (the one untested mechanism after
// r2-r14 all pinned at 39-42%): every prior version read tile kt's frags
// and consumed them in the SAME interval -> block-wide LDS burst (~1150cy,
// matrix idle) then MFMA burst (~1306cy, LDS idle) = serial sum. Here
// interval kt's MFMAs use frags ALREADY IN REGS (read during interval
// kt-1), so the matrix pipe starts at interval entry while af(kt+1) reads
// interleave into the MFMA stream and bf(kt+1) refills its regs after the
// last group (WAR on bf is in-order-safe). Values cross the barrier in
// REGISTERS; the ds_reads themselves all drain (lgkmcnt(0)) before each
// barrier -- r4's race (reads retiring past the barrier) cannot recur.
// Memory skeleton r12-verbatim: 4-slot circular LDS (A 4x16KB + B 4x16KB
// = 128KB), stage(kt+3) per interval, boundary vmcnt(4) = drain through
// tile kt+2 (next interval reads slot kt+2), tile kt+3's 4 loads ride the
// barrier (T4 counted). Slot (kt+3)&3 = (kt-1)&3's readers drained >=1
// barrier earlier. LDS swizzle r8-verbatim (measured 0 conflicts).
// Register budget (the binding constraint, r14's lesson): af 2x8x4 + bf
// 4x4 = 80 + acc 128 + addressing ~35 => ~245 <= 256 keeps 8 waves/CU.
__global__ __launch_bounds__(512, 2) void gemm256(
    const char* __restrict__ Ap, const char* __restrict__ Bp,
    const int* __restrict__ bias, const float* __restrict__ pa,
    const float* __restrict__ pb, int* __restrict__ out) {
  extern __shared__ __align__(16) char lds[];  // 131072 bytes

  const int tid = threadIdx.x;
  const int wid = tid >> 6;
  const int lane = tid & 63;

  // XCD-aware bijective swizzle (nwg = 512, % 8 == 0)
  const int nwg = gridDim.x;
  const int cpx = nwg >> 3;
  const int flat = blockIdx.x;
  const int wg = (flat & 7) * cpx + (flat >> 3);
  const int br = wg >> 4;  // 0..31 (M/256)
  const int bn = wg & 15;  // 0..15 (N/256)

  const int wr = wid >> 2;   // 0..1 -> M half (128 rows)
  const int wcol = wid & 3;  // 0..3 -> N quarter (64 cols)

  // --- staging (r12-verbatim): per-lane pre-swizzled global src, linear dest ---
  const int srow = tid >> 2;                        // 0..127
  const int schunk = (tid & 3) ^ ((tid >> 3) & 3);  // inverse-swizzled chunk
  const char* aSrc = Ap + (size_t)(br * 256 + srow) * K_DIM + schunk * 16;
  const char* bSrc = Bp + (size_t)(bn * 256 + srow) * K_DIM + schunk * 16;

  auto stage = [&](int kt) {
    const int s = (kt & 3) * 16384;
    const char* sa = aSrc + kt * 64;
    const char* sb2 = bSrc + kt * 64;
    char* da = lds + s + wid * 1024;
    char* db = lds + 65536 + s + wid * 1024;
    gload_lds16(sa, da);
    gload_lds16(sa + (size_t)128 * K_DIM, da + 8192);
    gload_lds16(sb2, db);
    gload_lds16(sb2 + (size_t)128 * K_DIM, db + 8192);
  };

  // --- fragment reads (r8/r12-verbatim pattern, measured conflict-free) ---
  const int lrow = lane & 15;
  const int fchunk = lane >> 4;                   // 16B k-chunk 0..3
  const int rchunk = fchunk ^ ((lrow >> 1) & 3);  // swizzled slot chunk
  const int aOff = (wr * 128 + lrow) * 64 + rchunk * 16;           // + mi*1024 + slot
  const int bOff = 65536 + (wcol * 64 + lrow) * 64 + rchunk * 16;  // + ni*1024 + slot

  v4i acc[8][4];
  {
    v4i z = {0, 0, 0, 0};
#pragma unroll
    for (int mi = 0; mi < 8; ++mi)
#pragma unroll
      for (int ni = 0; ni < 4; ++ni) acc[mi][ni] = z;
  }

  v4i afA[8], afB[8], bf[4];

  // prologue: stage tiles 0,1,2; drain tiles 0,1 (leave tile 2's 4 loads);
  // barrier (others' writes visible); preload tile-0 frags into regs
  stage(0); stage(1); stage(2);
  asm volatile("s_waitcnt vmcnt(4)" ::: "memory");
  __builtin_amdgcn_s_barrier();
#pragma unroll
  for (int mi = 0; mi < 8; ++mi) afA[mi] = *(const v4i*)&lds[aOff + mi * 1024];
#pragma unroll
  for (int ni = 0; ni < 4; ++ni) bf[ni] = *(const v4i*)&lds[bOff + ni * 1024];

#define INTERVAL(KT, AFC, AFN)                                                       \
  do {                                                                               \
    const int sbn = (((KT) + 1) & 3) * 16384;                                        \
    if ((KT) + 3 < NT) stage((KT) + 3);                                              \
    __builtin_amdgcn_sched_barrier(0);                                               \
    _Pragma("unroll") for (int mi = 0; mi < 8; ++mi) {                               \
      if ((KT) + 1 < NT) AFN[mi] = *(const v4i*)&lds[sbn + aOff + mi * 1024];        \
      __builtin_amdgcn_sched_barrier(0);                                             \
      __builtin_amdgcn_s_setprio(1);                                                 \
      _Pragma("unroll") for (int ni = 0; ni < 4; ++ni)                               \
          acc[mi][ni] = __builtin_amdgcn_mfma_i32_16x16x64_i8(AFC[mi], bf[ni],       \
                                                              acc[mi][ni], 0, 0, 0); \
      __builtin_amdgcn_s_setprio(0);                                                 \
      __builtin_amdgcn_sched_barrier(0);                                             \
    }                                                                                \
    if ((KT) + 1 < NT) {                                                             \
      _Pragma("unroll") for (int ni = 0; ni < 4; ++ni)                               \
          bf[ni] = *(const v4i*)&lds[sbn + bOff + ni * 1024];                        \
    }                                                                                \
    if ((KT) < NT - 3)                                                               \
      asm volatile("s_waitcnt vmcnt(4)" ::: "memory");                               \
    else                                                                             \
      asm volatile("s_waitcnt vmcnt(0)" ::: "memory");                               \
    asm volatile("s_waitcnt lgkmcnt(0)" ::: "memory");                               \
    __builtin_amdgcn_s_barrier();                                                    \
  } while (0)

  for (int kt = 0; kt < NT; kt += 2) {
    INTERVAL(kt, afA, afB);
    INTERVAL(kt + 1, afB, afA);
  }
#undef INTERVAL

  // epilogue: y = round(alpha*acc + beta*bias), clamp, write int32
  const float alpha = *pa;
  const float beta = *pb;
  const int rg = lane >> 4;
#pragma unroll
  for (int ni = 0; ni < 4; ++ni) {
    const int n = bn * 256 + wcol * 64 + ni * 16 + lrow;
    const float bb2 = __fmul_rn(beta, (float)bias[n]);
#pragma unroll
    for (int mi = 0; mi < 8; ++mi) {
#pragma unroll
      for (int j = 0; j < 4; ++j) {
        const int m = br * 256 + wr * 128 + mi * 16 + rg * 4 + j;
        float y = __fadd_rn(__fmul_rn(alpha, (float)acc[mi][ni][j]), bb2);
        y = rintf(y);
        y = fminf(127.f, fmaxf(-128.f, y));
        out[(size_t)m * N_DIM + n] = (int)y;
      }
    }
  }
}

extern "C" void kernel_launch(void* const* d_in, const int* in_sizes, int n_in,
                              void* d_out, int out_size, void* d_ws, size_t ws_size,
                              hipStream_t stream) {
  const int* x = (const int*)d_in[0];       // [M,K] int8 values in int32
  const int* w = (const int*)d_in[1];       // [N,K] int8 values in int32
  const int* bias = (const int*)d_in[2];    // [N] int8 values in int32
  const float* pa = (const float*)d_in[3];  // alpha
  const float* pb = (const float*)d_in[4];  // beta
  int* out = (int*)d_out;

  const int M = in_sizes[0] / K_DIM;  // 8192
  const size_t xBytes = (size_t)M * K_DIM;
  const size_t wBytes = (size_t)N_DIM * K_DIM;

  char* xp = (char*)d_ws;
  char* wp = xp + xBytes;
  const int n16x = (int)(xBytes / 16);
  const int n16 = (int)((xBytes + wBytes) / 16);
  pack_kernel<<<(n16 + 255) / 256, 256, 0, stream>>>(x, (const int*)d_in[1],
                                                     (int4*)xp, n16x, n16);

  const int nwg = (M / 256) * (N_DIM / 256);  // 512
  hipFuncSetAttribute((const void*)gemm256,
                      hipFuncAttributeMaxDynamicSharedMemorySize, 131072);
  gemm256<<<nwg, 512, 131072, stream>>>(xp, wp, bias, pa, pb, out);
}